// Round 3
// baseline (128.344 us; speedup 1.0000x reference)
//
#include <hip/hip_runtime.h>
#include <hip/hip_bf16.h>

#define NB   2
#define SKV  1024
#define NSQ  512
#define HIN  256
#define HA   128

// proj stores E = exp2(KSC*p) = e^{2p};  tanh(pk+pq) = 1 - 2/(Ek*Eq+1)
#define KSC   2.8853900817779268f
#define LOG2E 1.4426950408889634f

// ---------------- Kernel A: projections -> E = e^{2*proj} ----------------
// rows [0,2048): ek[r] = exp2(KSC*(kv[r]@W_kv + b_kv)); rows [2048,3072): eq
__global__ __launch_bounds__(128) void proj_kernel(
    const float* __restrict__ kv,
    const float* __restrict__ qy,
    const float* __restrict__ Wkv,
    const float* __restrict__ bkv,
    const float* __restrict__ Wq,
    const float* __restrict__ bq,
    float* __restrict__ ek,
    float* __restrict__ eq)
{
    const int t  = threadIdx.x;            // 0..127 = output channel a
    const int r0 = blockIdx.x * 8;         // 8 rows per block
    const bool is_q = (r0 >= NB * SKV);
    const float* __restrict__ src = is_q ? (qy + (size_t)(r0 - NB * SKV) * HIN)
                                         : (kv + (size_t)r0 * HIN);
    const float* __restrict__ W  = is_q ? Wq : Wkv;
    const float* __restrict__ bs = is_q ? bq : bkv;
    float* __restrict__ dst = is_q ? (eq + (size_t)(r0 - NB * SKV) * HA)
                                   : (ek + (size_t)r0 * HA);

    float a[8];
    #pragma unroll
    for (int i = 0; i < 8; ++i) a[i] = 0.f;

    // rows are block-uniform -> scalar (s_load) path; W is coalesced vector
    #pragma unroll 2
    for (int h = 0; h < HIN; h += 4) {
        float w0 = W[(h + 0) * HA + t];
        float w1 = W[(h + 1) * HA + t];
        float w2 = W[(h + 2) * HA + t];
        float w3 = W[(h + 3) * HA + t];
        #pragma unroll
        for (int i = 0; i < 8; ++i) {
            const float4 r = *(const float4*)(src + (size_t)i * HIN + h); // uniform
            a[i] = fmaf(r.x, w0, a[i]);
            a[i] = fmaf(r.y, w1, a[i]);
            a[i] = fmaf(r.z, w2, a[i]);
            a[i] = fmaf(r.w, w3, a[i]);
        }
    }
    const float bb = bs[t];
    #pragma unroll
    for (int i = 0; i < 8; ++i)
        dst[(size_t)i * HA + t] = __builtin_amdgcn_exp2f((a[i] + bb) * KSC);
}

// ---------------- Kernel B: fused score/softmax/output ----------------
// one block = 4 consecutive (b,q) rows; 512 threads (8 waves); grid 256
__global__ __launch_bounds__(512) void attn_kernel(
    const float* __restrict__ ek,          // (2048,128) = e^{2*pk}
    const float* __restrict__ eq,          // (1024,128) = e^{2*pq}
    const float* __restrict__ wv,          // (128)
    const float* __restrict__ bv,          // (1)
    const float* __restrict__ kv,          // (2048,256) f32
    float* __restrict__ out)               // [262144 out0][1048576 weights]
{
    __shared__ __align__(16) float eq_s[4][HA];
    __shared__ __align__(16) float wv_s[HA];
    __shared__ __align__(16) float wt_s[SKV][4];
    __shared__ float red[2][4][8];
    __shared__ float w0red[8];
    __shared__ __align__(16) float part[8][4][HIN]; // 32 KB

    const int tid  = threadIdx.x;
    const int lane = tid & 63, wid = tid >> 6;
    const int bq0  = blockIdx.x * 4;
    const int b    = bq0 >> 9;

    // ---- phase 1: stage Eq, wv; W0 = sum(wv) ----
    {
        const int row = tid >> 7, a = tid & 127;
        eq_s[row][a] = eq[(size_t)(bq0 + row) * HA + a];
    }
    float w0p = (tid < HA) ? wv[tid] : 0.f;
    if (tid < HA) wv_s[tid] = w0p;
    #pragma unroll
    for (int o = 32; o > 0; o >>= 1) w0p += __shfl_down(w0p, o);
    if (lane == 0) w0red[wid] = w0p;
    const float bvf = bv[0];
    __syncthreads();
    float W0 = 0.f;
    #pragma unroll
    for (int i = 0; i < 8; ++i) W0 += w0red[i];

    // ---- phase 2: scores for s0=tid, s1=tid+512, 4 q each ----
    // score = W0 + bv - 2*sum_a wv_a / (Ek*Eq + 1); paired rcp over (s0,s1)
    float acc[4][2];
    #pragma unroll
    for (int q = 0; q < 4; ++q) { acc[q][0] = 0.f; acc[q][1] = 0.f; }
    {
        const float4* __restrict__ e0row = (const float4*)(ek + (size_t)(b * SKV + tid) * HA);
        const float4* __restrict__ e1row = (const float4*)(ek + (size_t)(b * SKV + tid + 512) * HA);
        const float4* __restrict__ wv4 = (const float4*)wv_s;
        const float4* __restrict__ q40 = (const float4*)&eq_s[0][0];
        const float4* __restrict__ q41 = (const float4*)&eq_s[1][0];
        const float4* __restrict__ q42 = (const float4*)&eq_s[2][0];
        const float4* __restrict__ q43 = (const float4*)&eq_s[3][0];
        #pragma unroll 2
        for (int a4 = 0; a4 < 32; ++a4) {
            const float4 E0 = e0row[a4];
            const float4 E1 = e1row[a4];
            const float4 w4 = wv4[a4];
            float4 qq[4];
            qq[0] = q40[a4]; qq[1] = q41[a4]; qq[2] = q42[a4]; qq[3] = q43[a4];
            const float* Ep0 = (const float*)&E0;
            const float* Ep1 = (const float*)&E1;
            const float* Wp  = (const float*)&w4;
            #pragma unroll
            for (int c = 0; c < 4; ++c) {
                const float e0c = Ep0[c], e1c = Ep1[c], wc = Wp[c];
                #pragma unroll
                for (int q = 0; q < 4; ++q) {
                    const float qc = ((const float*)&qq[q])[c];
                    const float x  = fmaf(e0c, qc, 1.f);
                    const float y  = fmaf(e1c, qc, 1.f);
                    const float r  = __builtin_amdgcn_rcpf(x * y);
                    acc[q][0] = fmaf(wc, r * y, acc[q][0]);
                    acc[q][1] = fmaf(wc, r * x, acc[q][1]);
                }
            }
        }
    }
    float sc[4][2];
    #pragma unroll
    for (int q = 0; q < 4; ++q) {
        sc[q][0] = fmaf(-2.f, acc[q][0], W0) + bvf;
        sc[q][1] = fmaf(-2.f, acc[q][1], W0) + bvf;
    }

    // ---- phase 3: softmax over s ----
    #pragma unroll
    for (int q = 0; q < 4; ++q) {
        float m = fmaxf(sc[q][0], sc[q][1]);
        #pragma unroll
        for (int o = 32; o > 0; o >>= 1) m = fmaxf(m, __shfl_down(m, o));
        if (lane == 0) red[0][q][wid] = m;
    }
    __syncthreads();
    float M[4];
    #pragma unroll
    for (int q = 0; q < 4; ++q) {
        float m = red[0][q][0];
        #pragma unroll
        for (int i = 1; i < 8; ++i) m = fmaxf(m, red[0][q][i]);
        M[q] = m;
    }
    float e[4][2];
    #pragma unroll
    for (int q = 0; q < 4; ++q) {
        e[q][0] = __builtin_amdgcn_exp2f((sc[q][0] - M[q]) * LOG2E);
        e[q][1] = __builtin_amdgcn_exp2f((sc[q][1] - M[q]) * LOG2E);
        float sum = e[q][0] + e[q][1];
        #pragma unroll
        for (int o = 32; o > 0; o >>= 1) sum += __shfl_down(sum, o);
        if (lane == 0) red[1][q][wid] = sum;
    }
    __syncthreads();
    float rw[4];
    #pragma unroll
    for (int q = 0; q < 4; ++q) {
        float d = red[1][q][0];
        #pragma unroll
        for (int i = 1; i < 8; ++i) d += red[1][q][i];
        rw[q] = 1.0f / d;
    }

    float* __restrict__ outw = out + (size_t)NB * NSQ * HIN;   // weights at 262144
    #pragma unroll
    for (int si = 0; si < 2; ++si) {
        const int s = si * 512 + tid;
        #pragma unroll
        for (int q = 0; q < 4; ++q) {
            const float w = e[q][si] * rw[q];
            wt_s[s][q] = w;
            outw[(size_t)(bq0 + q) * SKV + s] = w;
        }
    }
    __syncthreads();

    // ---- phase 4: out[q][h] = sum_s w[q][s]*kv[b][s][h] ----
    {
        const int g = wid;                       // wave's s-chunk
        float4 ac0 = {0,0,0,0}, ac1 = {0,0,0,0}, ac2 = {0,0,0,0}, ac3 = {0,0,0,0};
        const float4* __restrict__ kvb =
            (const float4*)(kv + (size_t)(b * SKV + g * 128) * HIN);
        #pragma unroll 4
        for (int i = 0; i < 128; ++i) {
            const int s = g * 128 + i;
            const float4 w4 = *((const float4*)&wt_s[s][0]);   // LDS broadcast
            const float4 v  = kvb[(size_t)i * 64 + lane];      // coalesced
            ac0.x = fmaf(w4.x, v.x, ac0.x); ac0.y = fmaf(w4.x, v.y, ac0.y);
            ac0.z = fmaf(w4.x, v.z, ac0.z); ac0.w = fmaf(w4.x, v.w, ac0.w);
            ac1.x = fmaf(w4.y, v.x, ac1.x); ac1.y = fmaf(w4.y, v.y, ac1.y);
            ac1.z = fmaf(w4.y, v.z, ac1.z); ac1.w = fmaf(w4.y, v.w, ac1.w);
            ac2.x = fmaf(w4.z, v.x, ac2.x); ac2.y = fmaf(w4.z, v.y, ac2.y);
            ac2.z = fmaf(w4.z, v.z, ac2.z); ac2.w = fmaf(w4.z, v.w, ac2.w);
            ac3.x = fmaf(w4.w, v.x, ac3.x); ac3.y = fmaf(w4.w, v.y, ac3.y);
            ac3.z = fmaf(w4.w, v.z, ac3.z); ac3.w = fmaf(w4.w, v.w, ac3.w);
        }
        ((float4*)part[g][0])[lane] = ac0;
        ((float4*)part[g][1])[lane] = ac1;
        ((float4*)part[g][2])[lane] = ac2;
        ((float4*)part[g][3])[lane] = ac3;
    }
    __syncthreads();
    #pragma unroll
    for (int k = 0; k < 2; ++k) {
        const int id = tid + k * 512;
        const int q = id >> 8, h = id & 255;
        float v = 0.f;
        #pragma unroll
        for (int g2 = 0; g2 < 8; ++g2) v += part[g2][q][h];
        out[(size_t)(bq0 + q) * HIN + h] = v;
    }
}

extern "C" void kernel_launch(void* const* d_in, const int* in_sizes, int n_in,
                              void* d_out, int out_size, void* d_ws, size_t ws_size,
                              hipStream_t stream) {
    (void)in_sizes; (void)n_in; (void)out_size; (void)ws_size;
    const float* kv  = (const float*)d_in[0];
    const float* qy  = (const float*)d_in[1];
    const float* Wkv = (const float*)d_in[2];
    const float* bkv = (const float*)d_in[3];
    const float* Wq  = (const float*)d_in[4];
    const float* bq  = (const float*)d_in[5];
    const float* wv  = (const float*)d_in[6];
    const float* bv  = (const float*)d_in[7];

    float* ek = (float*)d_ws;                 // 2048*128 f32 = 1 MB
    float* eq = ek + (size_t)NB * SKV * HA;   // 1024*128 f32 = 0.5 MB
    float* out = (float*)d_out;

    hipLaunchKernelGGL(proj_kernel, dim3((NB * SKV + NB * NSQ) / 8), dim3(128), 0, stream,
                       kv, qy, Wkv, bkv, Wq, bq, ek, eq);
    hipLaunchKernelGGL(attn_kernel, dim3(NB * NSQ / 4), dim3(512), 0, stream,
                       ek, eq, wv, bv, kv, out);
}

// Round 4
// 124.586 us; speedup vs baseline: 1.0302x; 1.0302x over previous
//
#include <hip/hip_runtime.h>
#include <hip/hip_bf16.h>

#define NB   2
#define SKV  1024
#define NSQ  512
#define HIN  256
#define HA   128

// proj stores E = exp2(KSC*p) = e^{2p};  tanh(pk+pq) = 1 - 2/(Ek*Eq+1)
#define KSC   2.8853900817779268f
#define LOG2E 1.4426950408889634f

typedef float v2f __attribute__((ext_vector_type(2)));
__device__ __forceinline__ v2f pkfma(v2f a, v2f b, v2f c) {
    return __builtin_elementwise_fma(a, b, c);
}

// ---------------- K1: projections -> E = e^{2*proj} ----------------
// 8 rows/block, thread = (channel-quad c4, row r). No LDS, no uniform tricks.
__global__ __launch_bounds__(256) void proj_kernel(
    const float* __restrict__ kv,
    const float* __restrict__ qy,
    const float* __restrict__ Wkv,
    const float* __restrict__ bkv,
    const float* __restrict__ Wq,
    const float* __restrict__ bq,
    float* __restrict__ ek,
    float* __restrict__ eq)
{
    const int t  = threadIdx.x;
    const int c4 = (t & 31) * 4;          // channel quad
    const int r  = t >> 5;                // row in block, 0..7
    const int r0 = blockIdx.x * 8;
    const bool is_q = (r0 >= NB * SKV);
    const float* __restrict__ src = is_q ? (qy + (size_t)(r0 - NB * SKV) * HIN)
                                         : (kv + (size_t)r0 * HIN);
    const float* __restrict__ W  = is_q ? Wq : Wkv;
    const float* __restrict__ bs = is_q ? bq : bkv;
    float* __restrict__ dst = is_q ? (eq + (size_t)(r0 - NB * SKV) * HA)
                                   : (ek + (size_t)r0 * HA);

    const float* __restrict__ row = src + (size_t)r * HIN;
    v2f a0 = {0.f, 0.f}, a1 = {0.f, 0.f};
    #pragma unroll 4
    for (int h4 = 0; h4 < 64; ++h4) {
        const float4 x = *(const float4*)(row + h4 * 4);       // same-addr/32-lane, L1 bcast
        const float* Wb = W + (size_t)h4 * 4 * HA + c4;
        const float4 w0 = *(const float4*)(Wb);                // coalesced
        const float4 w1 = *(const float4*)(Wb + HA);
        const float4 w2 = *(const float4*)(Wb + 2 * HA);
        const float4 w3 = *(const float4*)(Wb + 3 * HA);
        a0 = pkfma((v2f){w0.x, w0.y}, (v2f){x.x, x.x}, a0);
        a1 = pkfma((v2f){w0.z, w0.w}, (v2f){x.x, x.x}, a1);
        a0 = pkfma((v2f){w1.x, w1.y}, (v2f){x.y, x.y}, a0);
        a1 = pkfma((v2f){w1.z, w1.w}, (v2f){x.y, x.y}, a1);
        a0 = pkfma((v2f){w2.x, w2.y}, (v2f){x.z, x.z}, a0);
        a1 = pkfma((v2f){w2.z, w2.w}, (v2f){x.z, x.z}, a1);
        a0 = pkfma((v2f){w3.x, w3.y}, (v2f){x.w, x.w}, a0);
        a1 = pkfma((v2f){w3.z, w3.w}, (v2f){x.w, x.w}, a1);
    }
    const float4 bb = *(const float4*)(bs + c4);
    float4 o;
    o.x = __builtin_amdgcn_exp2f((a0.x + bb.x) * KSC);
    o.y = __builtin_amdgcn_exp2f((a0.y + bb.y) * KSC);
    o.z = __builtin_amdgcn_exp2f((a1.x + bb.z) * KSC);
    o.w = __builtin_amdgcn_exp2f((a1.y + bb.w) * KSC);
    *(float4*)(dst + (size_t)r * HA + c4) = o;
}

// ---------------- K2: scores + exp (no max needed: |score| <= ~17) ----------
// block = (q-oct, s-half); 512 thr; writes ew (unnormalized) + Dpart
__global__ __launch_bounds__(512) void score_kernel(
    const float* __restrict__ ek,      // (2048,128) = e^{2*pk}
    const float* __restrict__ eq,      // (1024,128) = e^{2*pq}
    const float* __restrict__ wv,      // (128)
    const float* __restrict__ bv,      // (1)
    float* __restrict__ ew,            // (1024,1024) unnormalized exp(score)
    float* __restrict__ Dp)            // (2,1024) partial denominators
{
    __shared__ __align__(16) float4 eqs[8][32];
    __shared__ __align__(16) float4 wvs[32];
    __shared__ float w0red[8];
    __shared__ float dred[8][8];

    const int t    = threadIdx.x;
    const int lane = t & 63, wid = t >> 6;
    const int blk  = blockIdx.x;       // 0..255
    const int sh   = blk & 1;
    const int oct  = blk >> 1;         // 0..127 global q-oct
    const int q0   = oct * 8;          // global q row (= b*512 + local q)
    const int b    = q0 >> 9;
    const int s    = sh * 512 + t;     // kv index within b

    if (t < 256) {
        const int j = t >> 5, f = t & 31;
        eqs[j][f] = *((const float4*)(eq + (size_t)(q0 + j) * HA) + f);
    } else if (t < 288) {
        wvs[t - 256] = ((const float4*)wv)[t - 256];
    }
    float w0p = wv[t & 127];
    #pragma unroll
    for (int o = 32; o > 0; o >>= 1) w0p += __shfl_down(w0p, o);
    if (lane == 0) w0red[wid] = w0p;   // even waves: sum wv[0..63]; odd: wv[64..127]
    const float bvf = bv[0];
    __syncthreads();
    const float W0 = w0red[0] + w0red[1];

    // score = W0 + bv - 2*sum_a wv_a/(Ek_a*Eq_a + 1); quad-rcp, packed f32
    const float4* __restrict__ Erow4 = (const float4*)(ek + (size_t)(b * SKV + s) * HA);
    v2f acc[8];
    #pragma unroll
    for (int j = 0; j < 8; ++j) acc[j] = (v2f){0.f, 0.f};
    const v2f one = {1.f, 1.f};
    #pragma unroll 2
    for (int a4 = 0; a4 < 32; ++a4) {
        const float4 E  = Erow4[a4];
        const float4 w4 = wvs[a4];                 // LDS broadcast
        const v2f E01 = {E.x, E.y};
        const v2f E23 = {E.z, E.w};
        const v2f w01 = {w4.x, w4.y};
        const v2f w23 = {w4.z, w4.w};
        #pragma unroll
        for (int j = 0; j < 8; ++j) {
            const float4 qv = eqs[j][a4];          // LDS broadcast
            const v2f A  = pkfma(E01, (v2f){qv.x, qv.y}, one);
            const v2f B  = pkfma(E23, (v2f){qv.z, qv.w}, one);
            const v2f m  = A * B;                  // (x0*x2, x1*x3)
            const float r = __builtin_amdgcn_rcpf(m.x * m.y);
            const v2f ts = (v2f){m.y, m.x} * (v2f){r, r};   // (1/m.x, 1/m.y)
            acc[j] = pkfma(w01, ts * B, acc[j]);   // (w0/x0, w1/x1)
            acc[j] = pkfma(w23, ts * A, acc[j]);   // (w2/x2, w3/x3)
        }
    }

    float ev[8];
    #pragma unroll
    for (int j = 0; j < 8; ++j) {
        const float score = fmaf(-2.f, acc[j].x + acc[j].y, W0) + bvf;
        ev[j] = __builtin_amdgcn_exp2f(score * LOG2E);
        ew[(size_t)(q0 + j) * SKV + s] = ev[j];    // coalesced
    }
    #pragma unroll
    for (int j = 0; j < 8; ++j) {
        float ss = ev[j];
        #pragma unroll
        for (int o = 32; o > 0; o >>= 1) ss += __shfl_down(ss, o);
        if (lane == 0) dred[wid][j] = ss;
    }
    __syncthreads();
    if (t < 8) {
        float d = 0.f;
        #pragma unroll
        for (int w = 0; w < 8; ++w) d += dred[w][t];
        Dp[(size_t)sh * 1024 + q0 + t] = d;
    }
}

// ---------------- K3: output GEMM + normalize + weights write ---------------
// block = (q-oct, h-half); full s -> no cross-block reduction. grid 256.
__global__ __launch_bounds__(512) void out_kernel(
    const float* __restrict__ ew,
    const float* __restrict__ Dp,
    const float* __restrict__ kv,      // (2048,256)
    float* __restrict__ out)           // [262144 out0][1048576 weights]
{
    __shared__ __align__(16) float lds[SKV * 12]; // ewsT[s][12] 48KB; reused as part[8][8][128]
    __shared__ float rws[8];

    const int t    = threadIdx.x;
    const int lane = t & 63, wid = t >> 6;
    const int blk  = blockIdx.x;       // 0..255
    const int hh   = blk & 1;
    const int oct  = blk >> 1;
    const int q0   = oct * 8;
    const int b    = q0 >> 9;

    if (t < 8) rws[t] = 1.0f / (Dp[q0 + t] + Dp[1024 + q0 + t]);
    __syncthreads();
    float rw[8];
    #pragma unroll
    for (int j = 0; j < 8; ++j) rw[j] = rws[j];

    float* __restrict__ outw = out + (size_t)NB * NSQ * HIN;   // weights at 262144
    #pragma unroll
    for (int p = 0; p < 2; ++p) {
        const int s = wid * 128 + p * 64 + lane;
        float e[8];
        #pragma unroll
        for (int j = 0; j < 8; ++j) e[j] = ew[(size_t)(q0 + j) * SKV + s] * rw[j];
        if (hh == 0) {
            #pragma unroll
            for (int j = 0; j < 8; ++j) outw[(size_t)(q0 + j) * SKV + s] = e[j]; // coalesced
        }
        float* d = lds + (size_t)s * 12;
        *(float4*)(d)     = make_float4(e[0], e[1], e[2], e[3]);
        *(float4*)(d + 4) = make_float4(e[4], e[5], e[6], e[7]);
    }
    __syncthreads();

    // GEMM: thread = (h-quad hq, s-chunk sc0 of 64); acc[q] over 4 h
    const int hq  = t & 31;
    const int sc0 = t >> 5;            // 0..15
    const int h   = hh * 128 + hq * 4;
    const float* __restrict__ kvb = kv + (size_t)b * SKV * HIN + h;
    v2f acc[8][2];
    #pragma unroll
    for (int j = 0; j < 8; ++j) { acc[j][0] = (v2f){0.f, 0.f}; acc[j][1] = (v2f){0.f, 0.f}; }
    #pragma unroll 4
    for (int i = 0; i < 64; ++i) {
        const int s = sc0 * 64 + i;
        const float4 v = *(const float4*)(kvb + (size_t)s * HIN);   // coalesced
        const float* er = lds + (size_t)s * 12;
        const float4 e03 = *(const float4*)(er);                    // broadcast
        const float4 e47 = *(const float4*)(er + 4);
        const v2f vlo = {v.x, v.y}, vhi = {v.z, v.w};
        acc[0][0] = pkfma(vlo, (v2f){e03.x, e03.x}, acc[0][0]);
        acc[0][1] = pkfma(vhi, (v2f){e03.x, e03.x}, acc[0][1]);
        acc[1][0] = pkfma(vlo, (v2f){e03.y, e03.y}, acc[1][0]);
        acc[1][1] = pkfma(vhi, (v2f){e03.y, e03.y}, acc[1][1]);
        acc[2][0] = pkfma(vlo, (v2f){e03.z, e03.z}, acc[2][0]);
        acc[2][1] = pkfma(vhi, (v2f){e03.z, e03.z}, acc[2][1]);
        acc[3][0] = pkfma(vlo, (v2f){e03.w, e03.w}, acc[3][0]);
        acc[3][1] = pkfma(vhi, (v2f){e03.w, e03.w}, acc[3][1]);
        acc[4][0] = pkfma(vlo, (v2f){e47.x, e47.x}, acc[4][0]);
        acc[4][1] = pkfma(vhi, (v2f){e47.x, e47.x}, acc[4][1]);
        acc[5][0] = pkfma(vlo, (v2f){e47.y, e47.y}, acc[5][0]);
        acc[5][1] = pkfma(vhi, (v2f){e47.y, e47.y}, acc[5][1]);
        acc[6][0] = pkfma(vlo, (v2f){e47.z, e47.z}, acc[6][0]);
        acc[6][1] = pkfma(vhi, (v2f){e47.z, e47.z}, acc[6][1]);
        acc[7][0] = pkfma(vlo, (v2f){e47.w, e47.w}, acc[7][0]);
        acc[7][1] = pkfma(vhi, (v2f){e47.w, e47.w}, acc[7][1]);
    }

    // fold upper half-wave (adjacent s-chunk) into lower
    #pragma unroll
    for (int j = 0; j < 8; ++j) {
        #pragma unroll
        for (int k = 0; k < 2; ++k) {
            acc[j][k].x += __shfl_down(acc[j][k].x, 32);
            acc[j][k].y += __shfl_down(acc[j][k].y, 32);
        }
    }
    __syncthreads();                   // done reading ewsT; reuse lds as part[]
    if (lane < 32) {
        float* pp = lds + (size_t)wid * 1024 + hq * 4;
        #pragma unroll
        for (int j = 0; j < 8; ++j)
            *(float4*)(pp + (size_t)j * 128) =
                make_float4(acc[j][0].x, acc[j][0].y, acc[j][1].x, acc[j][1].y);
    }
    __syncthreads();
    #pragma unroll
    for (int k = 0; k < 2; ++k) {
        const int id = t + k * 512;
        const int j = id >> 7, hl = id & 127;
        float v = 0.f;
        #pragma unroll
        for (int g = 0; g < 8; ++g) v += lds[(size_t)g * 1024 + j * 128 + hl];
        out[(size_t)(q0 + j) * HIN + hh * 128 + hl] = v;   // coalesced
    }
}

extern "C" void kernel_launch(void* const* d_in, const int* in_sizes, int n_in,
                              void* d_out, int out_size, void* d_ws, size_t ws_size,
                              hipStream_t stream) {
    (void)in_sizes; (void)n_in; (void)out_size; (void)ws_size;
    const float* kv  = (const float*)d_in[0];
    const float* qy  = (const float*)d_in[1];
    const float* Wkv = (const float*)d_in[2];
    const float* bkv = (const float*)d_in[3];
    const float* Wq  = (const float*)d_in[4];
    const float* bq  = (const float*)d_in[5];
    const float* wv  = (const float*)d_in[6];
    const float* bv  = (const float*)d_in[7];

    float* ek = (float*)d_ws;          // 262144 f32
    float* eq = ek + 262144;           // 131072 f32
    float* ew = eq + 131072;           // 1048576 f32
    float* Dp = ew + 1048576;          // 2048 f32
    float* out = (float*)d_out;

    hipLaunchKernelGGL(proj_kernel, dim3(384), dim3(256), 0, stream,
                       kv, qy, Wkv, bkv, Wq, bq, ek, eq);
    hipLaunchKernelGGL(score_kernel, dim3(256), dim3(512), 0, stream,
                       ek, eq, wv, bv, ew, Dp);
    hipLaunchKernelGGL(out_kernel, dim3(256), dim3(512), 0, stream,
                       ew, Dp, kv, out);
}